// Round 3
// baseline (801.905 us; speedup 1.0000x reference)
//
#include <hip/hip_runtime.h>

#define G60 60
#define KN 13

typedef unsigned int u32;
typedef unsigned short u16;
typedef short short8 __attribute__((ext_vector_type(8)));
typedef float f32x4 __attribute__((ext_vector_type(4)));
typedef float f32x16 __attribute__((ext_vector_type(16)));
typedef u32 u32x4 __attribute__((ext_vector_type(4)));

// compile-time for loop: every index is a literal -> registers guaranteed
template <int I> struct Ic { static constexpr int v = I; };
template <int I, int N, typename F>
__device__ __forceinline__ void sfor(F&& f) {
    if constexpr (I < N) { f(Ic<I>{}); sfor<I + 1, N>(f); }
}

// ---- split-bf16 helpers ----------------------------------------------------
__device__ __forceinline__ u32 f32_to_packed(float v) {
    u32 u = __float_as_uint(v);
    u32 hi = (u + 0x7FFFu + ((u >> 16) & 1u)) >> 16;      // RNE bf16 of v
    float vhi = __uint_as_float(hi << 16);
    float lof = v - vhi;
    u32 ul = __float_as_uint(lof);
    u32 lo = (ul + 0x7FFFu + ((ul >> 16) & 1u)) >> 16;    // RNE bf16 of residual
    return (hi << 16) | lo;
}
__device__ __forceinline__ float packed_f32(u32 w) {
    return __uint_as_float(w & 0xFFFF0000u) + __uint_as_float(w << 16);
}

// ---- fused weight pack: all 4 layers in one dispatch -----------------------
// W[o][c][k] -> 32x32x16 MFMA B-frag order, hi/lo planes.
// chunk t = (ct*13 + kk)*SUBS + sub ; element id = ((t*NTt + nt)*64 + lane)*8 + j
// o = nt*32 + (lane&31); c = ct*CT + sub*16 + (lane>>5)*8 + j
__device__ __forceinline__ void pack_one(const float* __restrict__ W,
                                         u16* __restrict__ Whi, u16* __restrict__ Wlo,
                                         int C, int O, int CT, int id) {
    int j = id & 7;
    int lane = (id >> 3) & 63;
    int fid = id >> 9;
    int NTt = O >> 5;
    int nt = fid % NTt;
    int t = fid / NTt;
    int SUBS = CT >> 4;
    int sub = t % SUBS;
    int kk = (t / SUBS) % KN;
    int ct = t / (KN * SUBS);
    int q = lane >> 5, n = lane & 31;
    int o = nt * 32 + n;
    int c = ct * CT + sub * 16 + q * 8 + j;
    u32 pw = f32_to_packed(W[((size_t)o * C + c) * KN + kk]);
    Whi[id] = (u16)(pw >> 16);
    Wlo[id] = (u16)(pw & 0xFFFFu);
}

__global__ void __launch_bounds__(256) pack_all_kern(
    const float* W_in, u16* Whi_in, u16* Wlo_in,
    const float* W1, u16* Whi_1, u16* Wlo_1,
    const float* W2, u16* Whi_2, u16* Wlo_2,
    const float* Wo, u16* Whi_o, u16* Wlo_o) {
    const int T0 = KN * 32 * 256;            // conv_in (CT=32)
    const int T1 = T0 + KN * 256 * 512;      // conv1
    const int T2 = T1 + KN * 512 * 256;      // conv2
    const int T3 = T2 + KN * 256 * 32;       // conv_out
    int id = blockIdx.x * 256 + threadIdx.x;
    if (id < T0) pack_one(W_in, Whi_in, Wlo_in, 32, 256, 32, id);
    else if (id < T1) pack_one(W1, Whi_1, Wlo_1, 256, 512, 64, id - T0);
    else if (id < T2) pack_one(W2, Whi_2, Wlo_2, 512, 256, 64, id - T1);
    else if (id < T3) pack_one(Wo, Whi_o, Wlo_o, 256, 32, 64, id - T2);
}

// ---- 32x32x16 MFMA comb-conv, balanced roles + deep register pipeline ------
// 4 waves per block: wave w = (mg, ng); owns WM m-slots (of 2 batches x 2
// m-tiles) and WN n-tiles. WM=WN=2 balances per-CU per-K-step pipes: MFMA 775
// cyc (max), LDS ~590, B/L1 ~512. The remaining idle (~51% at rnd2) was
// latency exposure with 2 waves/SIMD: A ds_reads issued in the consuming
// group, B vmcnt at group boundaries with 1-group slack. Fix:
//   A regs double-buffered  (group g reads A for g+1;  ~1550 cyc slack)
//   B regs triple-buffered  (group g loads B for g+2;  ~3100 cyc slack)
//   s_setprio(1) around each group's MFMA cluster.
// MFMA sequence per accumulator unchanged -> bit-identical numerics.
// SRC: 0 packed u32, 1 fp32 (pack inline), 2 combine-2-fp32-partials+BN+ReLU
// +packed-residual. OUTF32: fp32 partial plane indexed by blockIdx.z.
template <int CT, int WM, int WN, int SRC, bool BNR, bool OUTF32>
__global__ void __launch_bounds__(256, 2) mconv9(
    const u32* __restrict__ Xp, const float* __restrict__ Xf,
    const float* __restrict__ pIn,
    const float* __restrict__ bnb, const float* __restrict__ bng,
    const float* __restrict__ bnB,
    const u32* __restrict__ resid,
    const u16* __restrict__ Whi, const u16* __restrict__ Wlo,
    const float* __restrict__ bias, const float* __restrict__ gamma,
    const float* __restrict__ beta,
    const int* __restrict__ nei,
    u32* __restrict__ outp, float* __restrict__ outf,
    int C, int O, int tpz) {
    constexpr int SUBS = CT >> 4;
    constexpr int S = KN * SUBS;           // K-steps per ct tile
    constexpr int NG = S / 2;              // groups of 2 steps
    constexpr int STRIDE = CT + 8;         // u16; rows 16B-aligned (72 or 40)
    constexpr int PLSZ = G60 * STRIDE;     // u16 per plane (16B-multiple)
    constexpr int NMG = 4 / WM;            // # m-groups
    __shared__ u16 Xs[4 * PLSZ];           // [bb][plane][PLSZ]
    const int tid = threadIdx.x;
    const int lane = tid & 63;
    const int wv = tid >> 6;
    const int mg = wv % NMG;               // wave's m-group
    const int ng = wv / NMG;               // wave's n-group
    const int q = lane >> 5;
    const int m = lane & 31;
    const int bp = blockIdx.x;             // batch-pair
    const int NTt = O >> 5;
    const int nt0 = (int)blockIdx.y * (WM * WN) + ng * WN;  // wave n-tile base
    const int ct0 = (int)blockIdx.z * tpz;
    const size_t PLi = (size_t)256 * C * G60;
    float* outfz = OUTF32 ? (outf + (size_t)blockIdx.z * ((size_t)256 * O * G60)) : nullptr;

    int rowoff[WM][KN];                    // own m-slots folded in (bb plane + nei row)
#pragma unroll
    for (int j = 0; j < WM; ++j) {
        int s = mg * WM + j;
        int bbs = s >> 1, mts = s & 1;
        int g = mts * 32 + m;
        int gl = (g < G60) ? g : 0;
#pragma unroll
        for (int kk = 0; kk < KN; ++kk)
            rowoff[j][kk] = nei[gl * KN + kk] * STRIDE + bbs * 2 * PLSZ;
    }

    f32x16 acc[WM][WN];
#pragma unroll
    for (int j = 0; j < WM; ++j)
#pragma unroll
        for (int nt = 0; nt < WN; ++nt) acc[j][nt] = (f32x16)(0.f);

    short8 Bh[3][2][WN], Bl[3][2][WN];     // [buf%3][step-in-group][nt]
    short8 Ah[2][2][WM], Al[2][2][WM];     // [buf&1][step-in-group][m-slot]

    for (int ct = ct0; ct < ct0 + tpz; ++ct) {
        const size_t fbase = ((size_t)(ct * S) * NTt + nt0) * 512 + (size_t)lane * 8;

        // B loader for compile-time group gg -> buffer gg%3
        auto loadB = [&](auto gt) {
            constexpr int gg = decltype(gt)::v;
            constexpr int bf = gg % 3;
            sfor<0, 2>([&](auto uc) {
                constexpr int u = decltype(uc)::v;
                constexpr int s = 2 * gg + u;
                sfor<0, WN>([&](auto nc) {
                    constexpr int nt = decltype(nc)::v;
                    const size_t fb = fbase + ((size_t)s * NTt + nt) * 512;
                    Bh[bf][u][nt] = *reinterpret_cast<const short8*>(Whi + fb);
                    Bl[bf][u][nt] = *reinterpret_cast<const short8*>(Wlo + fb);
                });
            });
        };
        // A loader for compile-time group gg -> buffer gg&1 (needs staged LDS)
        auto loadA = [&](auto gt) {
            constexpr int gg = decltype(gt)::v;
            constexpr int bf = gg & 1;
            sfor<0, 2>([&](auto uc) {
                constexpr int u = decltype(uc)::v;
                constexpr int s = 2 * gg + u;
                constexpr int kk = s / SUBS;
                constexpr int sub = s - kk * SUBS;
                sfor<0, WM>([&](auto jc) {
                    constexpr int j = decltype(jc)::v;
                    const int off = rowoff[j][kk] + sub * 16 + q * 8;
                    Ah[bf][u][j] = *reinterpret_cast<const short8*>(Xs + off);
                    Al[bf][u][j] = *reinterpret_cast<const short8*>(Xs + off + PLSZ);
                });
            });
        };

        __syncthreads();
        constexpr int PAIRS = (CT / 2) * G60;
        for (int i = tid; i < 2 * PAIRS; i += 256) {
            int sb = (i >= PAIRS) ? 1 : 0;
            int r = i - sb * PAIRS;
            int ccp = (r * 17477) >> 20;   // r/60, exact for r<3840
            int g = r - ccp * G60;
            int cc = ccp * 2;
            size_t cg0 = ((size_t)(bp * 2 + sb) * C + (size_t)ct * CT + cc) * G60 + g;
            u32 w0, w1;
            if (SRC == 0) {
                w0 = Xp[cg0]; w1 = Xp[cg0 + G60];
            } else if (SRC == 1) {
                w0 = f32_to_packed(Xf[cg0]); w1 = f32_to_packed(Xf[cg0 + G60]);
            } else {
                int c0 = ct * CT + cc;
                float v0 = pIn[cg0] + pIn[PLi + cg0];
                float v1 = pIn[cg0 + G60] + pIn[PLi + cg0 + G60];
                v0 = fmaxf((v0 + bnb[c0]) * bng[c0] + bnB[c0], 0.f) + packed_f32(resid[cg0]);
                v1 = fmaxf((v1 + bnb[c0 + 1]) * bng[c0 + 1] + bnB[c0 + 1], 0.f) + packed_f32(resid[cg0 + G60]);
                w0 = f32_to_packed(v0); w1 = f32_to_packed(v1);
            }
            int rb = sb * 2 * PLSZ + g * STRIDE + cc;
            *(u32*)(Xs + rb) = (w0 >> 16) | (w1 & 0xFFFF0000u);          // hi plane
            *(u32*)(Xs + rb + PLSZ) = (w0 & 0xFFFFu) | (w1 << 16);       // lo plane
        }

        // B prefetch for groups 0,1 issued before the barrier (LDS-independent)
        loadB(Ic<0>{});
        if constexpr (NG > 1) loadB(Ic<1>{});
        __syncthreads();

        loadA(Ic<0>{});                    // prime A pipeline for group 0

        sfor<0, NG>([&](auto gc) {
            constexpr int g = decltype(gc)::v;
            constexpr int b3 = g % 3;
            constexpr int ab = g & 1;
            if constexpr (g + 2 < NG) loadB(Ic<g + 2>{});   // B: 2 groups ahead
            if constexpr (g + 1 < NG) loadA(Ic<g + 1>{});   // A: 1 group ahead
            __builtin_amdgcn_s_setprio(1);
            // MFMAs: 3 passes x WM x WN per step; K-order per acc unchanged
            sfor<0, 2>([&](auto uc) {
                constexpr int u = decltype(uc)::v;
                sfor<0, WN>([&](auto nc) {
                    constexpr int nt = decltype(nc)::v;
                    sfor<0, WM>([&](auto jc) {
                        constexpr int j = decltype(jc)::v;
                        acc[j][nt] = __builtin_amdgcn_mfma_f32_32x32x16_bf16(
                            Ah[ab][u][j], Bh[b3][u][nt], acc[j][nt], 0, 0, 0);
                    });
                });
                sfor<0, WN>([&](auto nc) {
                    constexpr int nt = decltype(nc)::v;
                    sfor<0, WM>([&](auto jc) {
                        constexpr int j = decltype(jc)::v;
                        acc[j][nt] = __builtin_amdgcn_mfma_f32_32x32x16_bf16(
                            Ah[ab][u][j], Bl[b3][u][nt], acc[j][nt], 0, 0, 0);
                    });
                });
                sfor<0, WN>([&](auto nc) {
                    constexpr int nt = decltype(nc)::v;
                    sfor<0, WM>([&](auto jc) {
                        constexpr int j = decltype(jc)::v;
                        acc[j][nt] = __builtin_amdgcn_mfma_f32_32x32x16_bf16(
                            Al[ab][u][j], Bh[b3][u][nt], acc[j][nt], 0, 0, 0);
                    });
                });
            });
            __builtin_amdgcn_s_setprio(0);
        });
    }

    // epilogue. C/D: col(o)=lane&31, row-in-tile = (r&3)+8*(r>>2)+4*q [m74/m101]
#pragma unroll
    for (int j = 0; j < WM; ++j) {
        const int s = mg * WM + j;
        const int bbs = s >> 1, mts = s & 1;
        const int b = bp * 2 + bbs;
#pragma unroll
        for (int nt = 0; nt < WN; ++nt) {
            const int o = (nt0 + nt) * 32 + m;
            float bi = 0.f, ga = 1.f, be = 0.f;
            if (!OUTF32) { bi = bias[o]; if (BNR) { ga = gamma[o]; be = beta[o]; } }
#pragma unroll
            for (int grp = 0; grp < 4; ++grp) {
                const int g0 = mts * 32 + grp * 8 + q * 4;
                if (g0 < G60) {
                    size_t oi = ((size_t)b * O + o) * G60 + g0;
                    if (OUTF32) {
                        f32x4 v;
#pragma unroll
                        for (int rr = 0; rr < 4; ++rr) v[rr] = acc[j][nt][grp * 4 + rr];
                        *reinterpret_cast<f32x4*>(outfz + oi) = v;
                    } else {
                        u32x4 pv;
#pragma unroll
                        for (int rr = 0; rr < 4; ++rr) {
                            float v = acc[j][nt][grp * 4 + rr] + bi;
                            if (BNR) v = fmaxf(v * ga + be, 0.f);
                            pv[rr] = f32_to_packed(v);
                        }
                        *reinterpret_cast<u32x4*>(outp + oi) = pv;
                    }
                }
            }
        }
    }
}

// ---- finalize: sum 4 conv_out partials, BN+ReLU, +feats, norms; also emits
// the feats passthrough output (replaces the d2d memcpy dispatch). -----------
__global__ void __launch_bounds__(64) finalize_kern(
    const float* __restrict__ pout,          // [4][B][32][60] fp32 partials
    const float* __restrict__ feats,         // [B][32][60]
    const float* __restrict__ bo, const float* __restrict__ go,
    const float* __restrict__ beo,
    float* __restrict__ out_feats,           // [B][32][60] passthrough
    float* __restrict__ out_eqv,             // [B][32][60]
    float* __restrict__ out_inv) {           // [B][32]
    const int b = blockIdx.x;
    const size_t PB = (size_t)256 * 32 * G60;
    __shared__ float E[32 * G60];
    __shared__ float gnorm[G60];
    __shared__ float inv_pre[32];
    __shared__ float inv_nrm;
    const int tid = threadIdx.x;

    for (int i = tid; i < 32 * G60; i += 64) {
        int f = i / G60;
        size_t idx = (size_t)b * 1920 + i;
        float ft = feats[idx];
        out_feats[idx] = ft;
        float s = pout[idx] + pout[PB + idx] + pout[2 * PB + idx] + pout[3 * PB + idx];
        float v = fmaxf((s + bo[f]) * go[f] + beo[f], 0.f);
        E[i] = v + ft;
    }
    __syncthreads();
    if (tid < G60) {
        float s = 0.f;
        for (int f = 0; f < 32; ++f) { float v = E[f * G60 + tid]; s += v * v; }
        gnorm[tid] = fmaxf(sqrtf(s), 1e-4f);
    }
    if (tid < 32) {
        float s = 0.f;
        for (int g = 0; g < G60; ++g) s += E[tid * G60 + g];
        inv_pre[tid] = s / 60.f;
    }
    __syncthreads();
    if (tid == 0) {
        float s = 0.f;
        for (int f = 0; f < 32; ++f) s += inv_pre[f] * inv_pre[f];
        inv_nrm = fmaxf(sqrtf(s), 1e-4f);
    }
    __syncthreads();
    for (int i = tid; i < 1920; i += 64) {
        int g = i % G60;
        out_eqv[(size_t)b * 1920 + i] = E[i] / gnorm[g];
    }
    if (tid < 32) out_inv[b * 32 + tid] = inv_pre[tid] / inv_nrm;
}

// ---- des2dr: 256 thr/block, 4-way channel split per rotation a -------------
__global__ void __launch_bounds__(256) des2dr_kern(
    const float* __restrict__ e0f, const float* __restrict__ e1f,
    const int* __restrict__ permu, int* __restrict__ pre_int,
    float* __restrict__ out_pre) {
    const int b = blockIdx.x;
    __shared__ float X0[32 * G60];
    __shared__ float X1[32 * G60];
    __shared__ float pc[256];
    __shared__ float cor[64];
    const int tid = threadIdx.x;
    for (int i = tid; i < 1920; i += 256) {
        X0[i] = e0f[(size_t)b * 1920 + i];
        X1[i] = e1f[(size_t)b * 1920 + i];
    }
    __syncthreads();
    const int a = tid >> 2, fc = tid & 3;
    float s = 0.f;
    if (a < G60) {
        for (int g = 0; g < G60; ++g) {
            int p = permu[a * G60 + g];
#pragma unroll
            for (int f = fc * 8; f < fc * 8 + 8; ++f) s += X0[f * G60 + p] * X1[f * G60 + g];
        }
    }
    pc[tid] = s;
    __syncthreads();
    if (tid < 64) cor[tid] = pc[4 * tid] + pc[4 * tid + 1] + pc[4 * tid + 2] + pc[4 * tid + 3];
    __syncthreads();
    if (tid == 0) {
        float best = cor[0];
        int bi = 0;
        for (int a2 = 1; a2 < G60; ++a2)
            if (cor[a2] > best) { best = cor[a2]; bi = a2; }  // first-max = jnp.argmax
        pre_int[b] = bi;
        out_pre[b] = (float)bi;
    }
}

__global__ void __launch_bounds__(256) ability_kern(
    const int* __restrict__ pre_int, const int* __restrict__ true_idx,
    float* __restrict__ out_ability, float* __restrict__ out_true) {
    __shared__ int cnt[256];
    const int t = threadIdx.x;
    cnt[t] = (pre_int[t] == true_idx[t]) ? 1 : 0;
    out_true[t] = (float)true_idx[t];
    __syncthreads();
    for (int s = 128; s > 0; s >>= 1) {
        if (t < s) cnt[t] += cnt[t + s];
        __syncthreads();
    }
    if (t == 0) out_ability[0] = (float)cnt[0] / 256.0f;
}

extern "C" void kernel_launch(void* const* d_in, const int* in_sizes, int n_in,
                              void* d_out, int out_size, void* d_ws, size_t ws_size,
                              hipStream_t stream) {
    const float* feats0 = (const float*)d_in[0];
    const float* feats1 = (const float*)d_in[1];
    const int* true_idx = (const int*)d_in[2];
    const int* nei = (const int*)d_in[3];
    const int* permu = (const int*)d_in[4];
    const float* W_in = (const float*)d_in[5];
    const float* b_in = (const float*)d_in[6];
    const float* W1 = (const float*)d_in[7];
    const float* b1 = (const float*)d_in[8];
    const float* g1 = (const float*)d_in[9];
    const float* be1 = (const float*)d_in[10];
    const float* W2 = (const float*)d_in[11];
    const float* b2 = (const float*)d_in[12];
    const float* g2 = (const float*)d_in[13];
    const float* be2 = (const float*)d_in[14];
    const float* Wo = (const float*)d_in[15];
    const float* bo = (const float*)d_in[16];
    const float* go = (const float*)d_in[17];
    const float* beo = (const float*)d_in[18];

    float* out = (float*)d_out;
    const size_t SZF = (size_t)256 * 32 * G60;  // 491520
    float* out_f0 = out;
    float* out_f1 = out + SZF;
    float* out_e0 = out + 2 * SZF;
    float* out_e1 = out + 3 * SZF;
    float* out_i0 = out + 4 * SZF;
    float* out_i1 = out_i0 + 256 * 32;
    float* out_ab = out_i1 + 256 * 32;
    float* out_tr = out_ab + 1;
    float* out_pr = out_tr + 256;

    // ---- workspace layout (~101 MB, unchanged footprint) ----
    char* p = (char*)d_ws;
    auto alloc = [&](size_t bytes) { char* r = p; p += (bytes + 255) & ~(size_t)255; return r; };
    const size_t NW_IN = (size_t)KN * 32 * 256;
    const size_t NW_1 = (size_t)KN * 256 * 512;
    const size_t NW_2 = (size_t)KN * 512 * 256;
    const size_t NW_O = (size_t)KN * 256 * 32;
    u16* Whi_in = (u16*)alloc(NW_IN * 2); u16* Wlo_in = (u16*)alloc(NW_IN * 2);
    u16* Whi_1 = (u16*)alloc(NW_1 * 2);   u16* Wlo_1 = (u16*)alloc(NW_1 * 2);
    u16* Whi_2 = (u16*)alloc(NW_2 * 2);   u16* Wlo_2 = (u16*)alloc(NW_2 * 2);
    u16* Whi_o = (u16*)alloc(NW_O * 2);   u16* Wlo_o = (u16*)alloc(NW_O * 2);
    u32* dbuf = (u32*)alloc((size_t)256 * 256 * G60 * 4);        // conv_in out, packed
    u32* fcbuf = (u32*)alloc((size_t)256 * 512 * G60 * 4);       // conv1 out, packed
    float* p2 = (float*)alloc((size_t)2 * 256 * 256 * G60 * 4);  // conv2 K-split partials
    float* pout = (float*)alloc((size_t)4 * SZF * 4);            // conv_out K-split partials
    int* pre_int = (int*)alloc(256 * 4);

    // ---- fused weight pack (1 dispatch) ----
    {
        int total = KN * (32 * 256 + 256 * 512 + 512 * 256 + 256 * 32);
        pack_all_kern<<<dim3((total + 255) / 256), dim3(256), 0, stream>>>(
            W_in, Whi_in, Wlo_in, W1, Whi_1, Wlo_1, W2, Whi_2, Wlo_2, Wo, Whi_o, Wlo_o);
    }

    for (int net = 0; net < 2; ++net) {
        const float* feats = net ? feats1 : feats0;
        float* of = net ? out_f1 : out_f0;
        float* oe = net ? out_e1 : out_e0;
        float* oi = net ? out_i1 : out_i0;

        // conv_in: 32 -> 256, fp32 src packed inline. WM=2,WN=2, grid (128, 2).
        mconv9<32, 2, 2, 1, false, false><<<dim3(128, 2, 1), dim3(256), 0, stream>>>(
            nullptr, feats, nullptr, nullptr, nullptr, nullptr, nullptr,
            Whi_in, Wlo_in, b_in, nullptr, nullptr, nei, dbuf, nullptr, 32, 256, 1);
        // conv1: 256 -> 512, BN+ReLU packed. WM=2,WN=2, grid (128, 4).
        mconv9<64, 2, 2, 0, true, false><<<dim3(128, 4, 1), dim3(256), 0, stream>>>(
            dbuf, nullptr, nullptr, nullptr, nullptr, nullptr, nullptr,
            Whi_1, Wlo_1, b1, g1, be1, nei, fcbuf, nullptr, 256, 512, 4);
        // conv2: 512 -> 256, fp32 partials, z=2 K-split. WM=2,WN=2, grid (128, 2, 2).
        mconv9<64, 2, 2, 0, false, true><<<dim3(128, 2, 2), dim3(256), 0, stream>>>(
            fcbuf, nullptr, nullptr, nullptr, nullptr, nullptr, nullptr,
            Whi_2, Wlo_2, nullptr, nullptr, nullptr, nei, nullptr, p2, 512, 256, 4);
        // conv_out: 256 -> 32. Staging fuses p2 combine + b2/g2/be2 BN+ReLU
        // + residual(dbuf). fp32 partials z=4. WM=1,WN=1, grid (128, 1, 4).
        mconv9<64, 1, 1, 2, false, true><<<dim3(128, 1, 4), dim3(256), 0, stream>>>(
            nullptr, nullptr, p2, b2, g2, be2, dbuf,
            Whi_o, Wlo_o, nullptr, nullptr, nullptr, nei, nullptr, pout, 256, 32, 1);
        // finalize: sum partials + bo/go/beo BN+ReLU + feats + norms + passthrough
        finalize_kern<<<dim3(256), dim3(64), 0, stream>>>(pout, feats, bo, go, beo, of, oe, oi);
    }

    des2dr_kern<<<dim3(256), dim3(256), 0, stream>>>(out_e0, out_e1, permu, pre_int, out_pr);
    ability_kern<<<dim3(1), dim3(256), 0, stream>>>(pre_int, true_idx, out_ab, out_tr);

    (void)in_sizes; (void)n_in; (void)out_size; (void)ws_size;
}

// Round 4
// 774.010 us; speedup vs baseline: 1.0360x; 1.0360x over previous
//
#include <hip/hip_runtime.h>

#define G60 60
#define KN 13

typedef unsigned int u32;
typedef unsigned short u16;
typedef short short8 __attribute__((ext_vector_type(8)));
typedef float f32x4 __attribute__((ext_vector_type(4)));
typedef float f32x16 __attribute__((ext_vector_type(16)));
typedef u32 u32x4 __attribute__((ext_vector_type(4)));

// compile-time for loop: every index is a literal -> registers guaranteed
template <int I> struct Ic { static constexpr int v = I; };
template <int I, int N, typename F>
__device__ __forceinline__ void sfor(F&& f) {
    if constexpr (I < N) { f(Ic<I>{}); sfor<I + 1, N>(f); }
}

// ---- split-bf16 helpers ----------------------------------------------------
__device__ __forceinline__ u32 f32_to_packed(float v) {
    u32 u = __float_as_uint(v);
    u32 hi = (u + 0x7FFFu + ((u >> 16) & 1u)) >> 16;      // RNE bf16 of v
    float vhi = __uint_as_float(hi << 16);
    float lof = v - vhi;
    u32 ul = __float_as_uint(lof);
    u32 lo = (ul + 0x7FFFu + ((ul >> 16) & 1u)) >> 16;    // RNE bf16 of residual
    return (hi << 16) | lo;
}
__device__ __forceinline__ float packed_f32(u32 w) {
    return __uint_as_float(w & 0xFFFF0000u) + __uint_as_float(w << 16);
}

// ---- fused weight pack: all 4 layers in one dispatch -----------------------
// W[o][c][k] -> 32x32x16 MFMA B-frag order, hi/lo planes.
// chunk t = (ct*13 + kk)*SUBS + sub ; element id = ((t*NTt + nt)*64 + lane)*8 + j
// o = nt*32 + (lane&31); c = ct*CT + sub*16 + (lane>>5)*8 + j
__device__ __forceinline__ void pack_one(const float* __restrict__ W,
                                         u16* __restrict__ Whi, u16* __restrict__ Wlo,
                                         int C, int O, int CT, int id) {
    int j = id & 7;
    int lane = (id >> 3) & 63;
    int fid = id >> 9;
    int NTt = O >> 5;
    int nt = fid % NTt;
    int t = fid / NTt;
    int SUBS = CT >> 4;
    int sub = t % SUBS;
    int kk = (t / SUBS) % KN;
    int ct = t / (KN * SUBS);
    int q = lane >> 5, n = lane & 31;
    int o = nt * 32 + n;
    int c = ct * CT + sub * 16 + q * 8 + j;
    u32 pw = f32_to_packed(W[((size_t)o * C + c) * KN + kk]);
    Whi[id] = (u16)(pw >> 16);
    Wlo[id] = (u16)(pw & 0xFFFFu);
}

__global__ void __launch_bounds__(256) pack_all_kern(
    const float* W_in, u16* Whi_in, u16* Wlo_in,
    const float* W1, u16* Whi_1, u16* Wlo_1,
    const float* W2, u16* Whi_2, u16* Wlo_2,
    const float* Wo, u16* Whi_o, u16* Wlo_o) {
    const int T0 = KN * 32 * 256;            // conv_in (CT=32)
    const int T1 = T0 + KN * 256 * 512;      // conv1
    const int T2 = T1 + KN * 512 * 256;      // conv2
    const int T3 = T2 + KN * 256 * 32;       // conv_out
    int id = blockIdx.x * 256 + threadIdx.x;
    if (id < T0) pack_one(W_in, Whi_in, Wlo_in, 32, 256, 32, id);
    else if (id < T1) pack_one(W1, Whi_1, Wlo_1, 256, 512, 64, id - T0);
    else if (id < T2) pack_one(W2, Whi_2, Wlo_2, 512, 256, 64, id - T1);
    else if (id < T3) pack_one(Wo, Whi_o, Wlo_o, 256, 32, 64, id - T2);
}

// ---- 32x32x16 MFMA comb-conv, wave roles (WM m-slots x WN n-tiles) ---------
// 4 waves per block over 4 m-slots (2 batches x 2 m-tiles) and WM*WN block
// n-tiles. Wave w: mg = w % (4/WM) owns m-slots mg*WM..+WM-1; ng = w / (4/WM)
// owns n-tiles ng*WN..+WN-1.
// Measured pipe-sum law (per-CU, conv1-sized): LDS_A 66.6/WN + conflicts +
// B 177.6/(NB*WM) + MFMA 16.6 us; occupancy caps NB*WM*WN<=8. WM=4,WN=1 is
// the measured optimum (147 us; WM=2,WN=2 -> 159; WN=4 -> 186): B-redundancy
// costs more per byte (L1+latency) than LDS A-redundancy.
// rowoff holds only the 2 mt rows; the bb-plane offset folds as a
// compile-time constant for WM=4 (mg==0) -> ~64 VGPR like mconv6.
// SRC: 0 packed u32, 1 fp32 (pack inline), 2 combine-2-fp32-partials+BN+ReLU
// +packed-residual. OUTF32: fp32 partial plane indexed by blockIdx.z.
template <int CT, int WM, int WN, int SRC, bool BNR, bool OUTF32>
__global__ void __launch_bounds__(256, 2) mconv10(
    const u32* __restrict__ Xp, const float* __restrict__ Xf,
    const float* __restrict__ pIn,
    const float* __restrict__ bnb, const float* __restrict__ bng,
    const float* __restrict__ bnB,
    const u32* __restrict__ resid,
    const u16* __restrict__ Whi, const u16* __restrict__ Wlo,
    const float* __restrict__ bias, const float* __restrict__ gamma,
    const float* __restrict__ beta,
    const int* __restrict__ nei,
    u32* __restrict__ outp, float* __restrict__ outf,
    int C, int O, int tpz) {
    constexpr int SUBS = CT >> 4;
    constexpr int S = KN * SUBS;           // K-steps per ct tile
    constexpr int NG = S / 2;              // groups of 2 steps
    constexpr int STRIDE = CT + 8;         // u16; rows 16B-aligned (72 or 40)
    constexpr int PLSZ = G60 * STRIDE;     // u16 per plane (16B-multiple)
    constexpr int NMG = 4 / WM;            // # m-groups
    constexpr int NRO = (WM == 4) ? 2 : WM;  // rowoff entries actually needed
    __shared__ u16 Xs[4 * PLSZ];           // [bb][plane][PLSZ]
    const int tid = threadIdx.x;
    const int lane = tid & 63;
    const int wv = tid >> 6;
    const int mg = wv % NMG;               // wave's m-group
    const int ng = wv / NMG;               // wave's n-group
    const int q = lane >> 5;
    const int m = lane & 31;
    const int bp = blockIdx.x;             // batch-pair
    const int NTt = O >> 5;
    const int nt0 = (int)blockIdx.y * (WM * WN) + ng * WN;  // wave n-tile base
    const int ct0 = (int)blockIdx.z * tpz;
    const size_t PLi = (size_t)256 * C * G60;
    float* outfz = OUTF32 ? (outf + (size_t)blockIdx.z * ((size_t)256 * O * G60)) : nullptr;

    // rowoff: nei-gathered row offsets. WM==4: indexed by mt (bb-plane offset
    // is a compile-time constant at use, since mg==0). WM<=2: one entry per
    // owned m-slot with bb-plane offset folded at init.
    int rowoff[NRO][KN];
#pragma unroll
    for (int jj = 0; jj < NRO; ++jj) {
        int mts, base;
        if (WM == 4) { mts = jj; base = 0; }
        else {
            int s = mg * WM + jj;
            mts = s & 1;
            base = (s >> 1) * 2 * PLSZ;
        }
        int g = mts * 32 + m;
        int gl = (g < G60) ? g : 0;
#pragma unroll
        for (int kk = 0; kk < KN; ++kk)
            rowoff[jj][kk] = nei[gl * KN + kk] * STRIDE + base;
    }

    f32x16 acc[WM][WN];
#pragma unroll
    for (int j = 0; j < WM; ++j)
#pragma unroll
        for (int nt = 0; nt < WN; ++nt) acc[j][nt] = (f32x16)(0.f);

    short8 Bh[2][2][WN], Bl[2][2][WN];     // [buf][step-in-group][nt]

    for (int ct = ct0; ct < ct0 + tpz; ++ct) {
        const size_t fbase = ((size_t)(ct * S) * NTt + nt0) * 512 + (size_t)lane * 8;

        __syncthreads();
        constexpr int PAIRS = (CT / 2) * G60;
        for (int i = tid; i < 2 * PAIRS; i += 256) {
            int sb = (i >= PAIRS) ? 1 : 0;
            int r = i - sb * PAIRS;
            int ccp = (r * 17477) >> 20;   // r/60, exact for r<3840
            int g = r - ccp * G60;
            int cc = ccp * 2;
            size_t cg0 = ((size_t)(bp * 2 + sb) * C + (size_t)ct * CT + cc) * G60 + g;
            u32 w0, w1;
            if (SRC == 0) {
                w0 = Xp[cg0]; w1 = Xp[cg0 + G60];
            } else if (SRC == 1) {
                w0 = f32_to_packed(Xf[cg0]); w1 = f32_to_packed(Xf[cg0 + G60]);
            } else {
                int c0 = ct * CT + cc;
                float v0 = pIn[cg0] + pIn[PLi + cg0];
                float v1 = pIn[cg0 + G60] + pIn[PLi + cg0 + G60];
                v0 = fmaxf((v0 + bnb[c0]) * bng[c0] + bnB[c0], 0.f) + packed_f32(resid[cg0]);
                v1 = fmaxf((v1 + bnb[c0 + 1]) * bng[c0 + 1] + bnB[c0 + 1], 0.f) + packed_f32(resid[cg0 + G60]);
                w0 = f32_to_packed(v0); w1 = f32_to_packed(v1);
            }
            int rb = sb * 2 * PLSZ + g * STRIDE + cc;
            *(u32*)(Xs + rb) = (w0 >> 16) | (w1 & 0xFFFF0000u);          // hi plane
            *(u32*)(Xs + rb + PLSZ) = (w0 & 0xFFFFu) | (w1 << 16);       // lo plane
        }

        // group-0 B prefetch issued before the barrier (independent of LDS)
        sfor<0, 2>([&](auto uc) {
            constexpr int u = decltype(uc)::v;
            sfor<0, WN>([&](auto nc) {
                constexpr int nt = decltype(nc)::v;
                const size_t fb = fbase + ((size_t)u * NTt + nt) * 512;
                Bh[0][u][nt] = *reinterpret_cast<const short8*>(Whi + fb);
                Bl[0][u][nt] = *reinterpret_cast<const short8*>(Wlo + fb);
            });
        });
        __syncthreads();

        sfor<0, NG>([&](auto gc) {
            constexpr int g = decltype(gc)::v;
            constexpr int pb = g & 1;
            if constexpr (g + 1 < NG) {
                constexpr int pn = (g + 1) & 1;
                sfor<0, 2>([&](auto uc) {
                    constexpr int u = decltype(uc)::v;
                    constexpr int s = 2 * (g + 1) + u;
                    sfor<0, WN>([&](auto nc) {
                        constexpr int nt = decltype(nc)::v;
                        const size_t fb = fbase + ((size_t)s * NTt + nt) * 512;
                        Bh[pn][u][nt] = *reinterpret_cast<const short8*>(Whi + fb);
                        Bl[pn][u][nt] = *reinterpret_cast<const short8*>(Wlo + fb);
                    });
                });
            }
            // A fragments for group g: this wave's WM m-slots
            short8 Ah[2][WM], Al[2][WM];
            sfor<0, 2>([&](auto uc) {
                constexpr int u = decltype(uc)::v;
                constexpr int s = 2 * g + u;
                constexpr int kk = s / SUBS;
                constexpr int sub = s - kk * SUBS;
                sfor<0, WM>([&](auto jc) {
                    constexpr int j = decltype(jc)::v;
                    int off;
                    if constexpr (WM == 4)
                        off = rowoff[j & 1][kk] + (j >> 1) * 2 * PLSZ + sub * 16 + q * 8;
                    else
                        off = rowoff[j][kk] + sub * 16 + q * 8;
                    Ah[u][j] = *reinterpret_cast<const short8*>(Xs + off);
                    Al[u][j] = *reinterpret_cast<const short8*>(Xs + off + PLSZ);
                });
            });
            // MFMAs: 3 passes x WM x WN per step; K-order per acc unchanged
            sfor<0, 2>([&](auto uc) {
                constexpr int u = decltype(uc)::v;
                sfor<0, WN>([&](auto nc) {
                    constexpr int nt = decltype(nc)::v;
                    sfor<0, WM>([&](auto jc) {
                        constexpr int j = decltype(jc)::v;
                        acc[j][nt] = __builtin_amdgcn_mfma_f32_32x32x16_bf16(
                            Ah[u][j], Bh[pb][u][nt], acc[j][nt], 0, 0, 0);
                    });
                });
                sfor<0, WN>([&](auto nc) {
                    constexpr int nt = decltype(nc)::v;
                    sfor<0, WM>([&](auto jc) {
                        constexpr int j = decltype(jc)::v;
                        acc[j][nt] = __builtin_amdgcn_mfma_f32_32x32x16_bf16(
                            Ah[u][j], Bl[pb][u][nt], acc[j][nt], 0, 0, 0);
                    });
                });
                sfor<0, WN>([&](auto nc) {
                    constexpr int nt = decltype(nc)::v;
                    sfor<0, WM>([&](auto jc) {
                        constexpr int j = decltype(jc)::v;
                        acc[j][nt] = __builtin_amdgcn_mfma_f32_32x32x16_bf16(
                            Al[u][j], Bh[pb][u][nt], acc[j][nt], 0, 0, 0);
                    });
                });
            });
        });
    }

    // epilogue. C/D: col(o)=lane&31, row-in-tile = (r&3)+8*(r>>2)+4*q [m74/m101]
#pragma unroll
    for (int j = 0; j < WM; ++j) {
        const int s = mg * WM + j;
        const int bbs = s >> 1, mts = s & 1;
        const int b = bp * 2 + bbs;
#pragma unroll
        for (int nt = 0; nt < WN; ++nt) {
            const int o = (nt0 + nt) * 32 + m;
            float bi = 0.f, ga = 1.f, be = 0.f;
            if (!OUTF32) { bi = bias[o]; if (BNR) { ga = gamma[o]; be = beta[o]; } }
#pragma unroll
            for (int grp = 0; grp < 4; ++grp) {
                const int g0 = mts * 32 + grp * 8 + q * 4;
                if (g0 < G60) {
                    size_t oi = ((size_t)b * O + o) * G60 + g0;
                    if (OUTF32) {
                        f32x4 v;
#pragma unroll
                        for (int rr = 0; rr < 4; ++rr) v[rr] = acc[j][nt][grp * 4 + rr];
                        *reinterpret_cast<f32x4*>(outfz + oi) = v;
                    } else {
                        u32x4 pv;
#pragma unroll
                        for (int rr = 0; rr < 4; ++rr) {
                            float v = acc[j][nt][grp * 4 + rr] + bi;
                            if (BNR) v = fmaxf(v * ga + be, 0.f);
                            pv[rr] = f32_to_packed(v);
                        }
                        *reinterpret_cast<u32x4*>(outp + oi) = pv;
                    }
                }
            }
        }
    }
}

// ---- finalize: sum 4 conv_out partials, BN+ReLU, +feats, norms; also emits
// the feats passthrough output (replaces the d2d memcpy dispatch). -----------
__global__ void __launch_bounds__(64) finalize_kern(
    const float* __restrict__ pout,          // [4][B][32][60] fp32 partials
    const float* __restrict__ feats,         // [B][32][60]
    const float* __restrict__ bo, const float* __restrict__ go,
    const float* __restrict__ beo,
    float* __restrict__ out_feats,           // [B][32][60] passthrough
    float* __restrict__ out_eqv,             // [B][32][60]
    float* __restrict__ out_inv) {           // [B][32]
    const int b = blockIdx.x;
    const size_t PB = (size_t)256 * 32 * G60;
    __shared__ float E[32 * G60];
    __shared__ float gnorm[G60];
    __shared__ float inv_pre[32];
    __shared__ float inv_nrm;
    const int tid = threadIdx.x;

    for (int i = tid; i < 32 * G60; i += 64) {
        int f = i / G60;
        size_t idx = (size_t)b * 1920 + i;
        float ft = feats[idx];
        out_feats[idx] = ft;
        float s = pout[idx] + pout[PB + idx] + pout[2 * PB + idx] + pout[3 * PB + idx];
        float v = fmaxf((s + bo[f]) * go[f] + beo[f], 0.f);
        E[i] = v + ft;
    }
    __syncthreads();
    if (tid < G60) {
        float s = 0.f;
        for (int f = 0; f < 32; ++f) { float v = E[f * G60 + tid]; s += v * v; }
        gnorm[tid] = fmaxf(sqrtf(s), 1e-4f);
    }
    if (tid < 32) {
        float s = 0.f;
        for (int g = 0; g < G60; ++g) s += E[tid * G60 + g];
        inv_pre[tid] = s / 60.f;
    }
    __syncthreads();
    if (tid == 0) {
        float s = 0.f;
        for (int f = 0; f < 32; ++f) s += inv_pre[f] * inv_pre[f];
        inv_nrm = fmaxf(sqrtf(s), 1e-4f);
    }
    __syncthreads();
    for (int i = tid; i < 1920; i += 64) {
        int g = i % G60;
        out_eqv[(size_t)b * 1920 + i] = E[i] / gnorm[g];
    }
    if (tid < 32) out_inv[b * 32 + tid] = inv_pre[tid] / inv_nrm;
}

// ---- des2dr: 256 thr/block, 4-way channel split per rotation a -------------
__global__ void __launch_bounds__(256) des2dr_kern(
    const float* __restrict__ e0f, const float* __restrict__ e1f,
    const int* __restrict__ permu, int* __restrict__ pre_int,
    float* __restrict__ out_pre) {
    const int b = blockIdx.x;
    __shared__ float X0[32 * G60];
    __shared__ float X1[32 * G60];
    __shared__ float pc[256];
    __shared__ float cor[64];
    const int tid = threadIdx.x;
    for (int i = tid; i < 1920; i += 256) {
        X0[i] = e0f[(size_t)b * 1920 + i];
        X1[i] = e1f[(size_t)b * 1920 + i];
    }
    __syncthreads();
    const int a = tid >> 2, fc = tid & 3;
    float s = 0.f;
    if (a < G60) {
        for (int g = 0; g < G60; ++g) {
            int p = permu[a * G60 + g];
#pragma unroll
            for (int f = fc * 8; f < fc * 8 + 8; ++f) s += X0[f * G60 + p] * X1[f * G60 + g];
        }
    }
    pc[tid] = s;
    __syncthreads();
    if (tid < 64) cor[tid] = pc[4 * tid] + pc[4 * tid + 1] + pc[4 * tid + 2] + pc[4 * tid + 3];
    __syncthreads();
    if (tid == 0) {
        float best = cor[0];
        int bi = 0;
        for (int a2 = 1; a2 < G60; ++a2)
            if (cor[a2] > best) { best = cor[a2]; bi = a2; }  // first-max = jnp.argmax
        pre_int[b] = bi;
        out_pre[b] = (float)bi;
    }
}

__global__ void __launch_bounds__(256) ability_kern(
    const int* __restrict__ pre_int, const int* __restrict__ true_idx,
    float* __restrict__ out_ability, float* __restrict__ out_true) {
    __shared__ int cnt[256];
    const int t = threadIdx.x;
    cnt[t] = (pre_int[t] == true_idx[t]) ? 1 : 0;
    out_true[t] = (float)true_idx[t];
    __syncthreads();
    for (int s = 128; s > 0; s >>= 1) {
        if (t < s) cnt[t] += cnt[t + s];
        __syncthreads();
    }
    if (t == 0) out_ability[0] = (float)cnt[0] / 256.0f;
}

extern "C" void kernel_launch(void* const* d_in, const int* in_sizes, int n_in,
                              void* d_out, int out_size, void* d_ws, size_t ws_size,
                              hipStream_t stream) {
    const float* feats0 = (const float*)d_in[0];
    const float* feats1 = (const float*)d_in[1];
    const int* true_idx = (const int*)d_in[2];
    const int* nei = (const int*)d_in[3];
    const int* permu = (const int*)d_in[4];
    const float* W_in = (const float*)d_in[5];
    const float* b_in = (const float*)d_in[6];
    const float* W1 = (const float*)d_in[7];
    const float* b1 = (const float*)d_in[8];
    const float* g1 = (const float*)d_in[9];
    const float* be1 = (const float*)d_in[10];
    const float* W2 = (const float*)d_in[11];
    const float* b2 = (const float*)d_in[12];
    const float* g2 = (const float*)d_in[13];
    const float* be2 = (const float*)d_in[14];
    const float* Wo = (const float*)d_in[15];
    const float* bo = (const float*)d_in[16];
    const float* go = (const float*)d_in[17];
    const float* beo = (const float*)d_in[18];

    float* out = (float*)d_out;
    const size_t SZF = (size_t)256 * 32 * G60;  // 491520
    float* out_f0 = out;
    float* out_f1 = out + SZF;
    float* out_e0 = out + 2 * SZF;
    float* out_e1 = out + 3 * SZF;
    float* out_i0 = out + 4 * SZF;
    float* out_i1 = out_i0 + 256 * 32;
    float* out_ab = out_i1 + 256 * 32;
    float* out_tr = out_ab + 1;
    float* out_pr = out_tr + 256;

    // ---- workspace layout (~101 MB, unchanged footprint) ----
    char* p = (char*)d_ws;
    auto alloc = [&](size_t bytes) { char* r = p; p += (bytes + 255) & ~(size_t)255; return r; };
    const size_t NW_IN = (size_t)KN * 32 * 256;
    const size_t NW_1 = (size_t)KN * 256 * 512;
    const size_t NW_2 = (size_t)KN * 512 * 256;
    const size_t NW_O = (size_t)KN * 256 * 32;
    u16* Whi_in = (u16*)alloc(NW_IN * 2); u16* Wlo_in = (u16*)alloc(NW_IN * 2);
    u16* Whi_1 = (u16*)alloc(NW_1 * 2);   u16* Wlo_1 = (u16*)alloc(NW_1 * 2);
    u16* Whi_2 = (u16*)alloc(NW_2 * 2);   u16* Wlo_2 = (u16*)alloc(NW_2 * 2);
    u16* Whi_o = (u16*)alloc(NW_O * 2);   u16* Wlo_o = (u16*)alloc(NW_O * 2);
    u32* dbuf = (u32*)alloc((size_t)256 * 256 * G60 * 4);        // conv_in out, packed
    u32* fcbuf = (u32*)alloc((size_t)256 * 512 * G60 * 4);       // conv1 out, packed
    float* p2 = (float*)alloc((size_t)2 * 256 * 256 * G60 * 4);  // conv2 K-split partials
    float* pout = (float*)alloc((size_t)4 * SZF * 4);            // conv_out K-split partials
    int* pre_int = (int*)alloc(256 * 4);

    // ---- fused weight pack (1 dispatch) ----
    {
        int total = KN * (32 * 256 + 256 * 512 + 512 * 256 + 256 * 32);
        pack_all_kern<<<dim3((total + 255) / 256), dim3(256), 0, stream>>>(
            W_in, Whi_in, Wlo_in, W1, Whi_1, Wlo_1, W2, Whi_2, Wlo_2, Wo, Whi_o, Wlo_o);
    }

    for (int net = 0; net < 2; ++net) {
        const float* feats = net ? feats1 : feats0;
        float* of = net ? out_f1 : out_f0;
        float* oe = net ? out_e1 : out_e0;
        float* oi = net ? out_i1 : out_i0;

        // conv_in: 32 -> 256, fp32 src packed inline. WM=2,WN=1 -> 512 blocks,
        // 2 blocks/CU (was 1/CU at WN=2). grid (128, 4).
        mconv10<32, 2, 1, 1, false, false><<<dim3(128, 4, 1), dim3(256), 0, stream>>>(
            nullptr, feats, nullptr, nullptr, nullptr, nullptr, nullptr,
            Whi_in, Wlo_in, b_in, nullptr, nullptr, nei, dbuf, nullptr, 32, 256, 1);
        // conv1: 256 -> 512, BN+ReLU packed. WM=4,WN=1 (measured-best mconv6
        // geometry: B-traffic minimal). grid (128, 4).
        mconv10<64, 4, 1, 0, true, false><<<dim3(128, 4, 1), dim3(256), 0, stream>>>(
            dbuf, nullptr, nullptr, nullptr, nullptr, nullptr, nullptr,
            Whi_1, Wlo_1, b1, g1, be1, nei, fcbuf, nullptr, 256, 512, 4);
        // conv2: 512 -> 256, fp32 partials, z=2 K-split. WM=4,WN=1. grid (128, 2, 2).
        mconv10<64, 4, 1, 0, false, true><<<dim3(128, 2, 2), dim3(256), 0, stream>>>(
            fcbuf, nullptr, nullptr, nullptr, nullptr, nullptr, nullptr,
            Whi_2, Wlo_2, nullptr, nullptr, nullptr, nei, nullptr, p2, 512, 256, 4);
        // conv_out: 256 -> 32. Staging fuses p2 combine + b2/g2/be2 BN+ReLU
        // + residual(dbuf). fp32 partials z=4. WM=1,WN=1, grid (128, 1, 4).
        mconv10<64, 1, 1, 2, false, true><<<dim3(128, 1, 4), dim3(256), 0, stream>>>(
            nullptr, nullptr, p2, b2, g2, be2, dbuf,
            Whi_o, Wlo_o, nullptr, nullptr, nullptr, nei, nullptr, pout, 256, 32, 1);
        // finalize: sum partials + bo/go/beo BN+ReLU + feats + norms + passthrough
        finalize_kern<<<dim3(256), dim3(64), 0, stream>>>(pout, feats, bo, go, beo, of, oe, oi);
    }

    des2dr_kern<<<dim3(256), dim3(256), 0, stream>>>(out_e0, out_e1, permu, pre_int, out_pr);
    ability_kern<<<dim3(1), dim3(256), 0, stream>>>(pre_int, true_idx, out_ab, out_tr);

    (void)in_sizes; (void)n_in; (void)out_size; (void)ws_size;
}

// Round 5
// 720.924 us; speedup vs baseline: 1.1123x; 1.0736x over previous
//
#include <hip/hip_runtime.h>

#define G60 60
#define KN 13

typedef unsigned int u32;
typedef unsigned short u16;
typedef short short8 __attribute__((ext_vector_type(8)));
typedef float f32x4 __attribute__((ext_vector_type(4)));
typedef float f32x16 __attribute__((ext_vector_type(16)));
typedef u32 u32x4 __attribute__((ext_vector_type(4)));

// compile-time for loop: every index is a literal -> registers guaranteed
template <int I> struct Ic { static constexpr int v = I; };
template <int I, int N, typename F>
__device__ __forceinline__ void sfor(F&& f) {
    if constexpr (I < N) { f(Ic<I>{}); sfor<I + 1, N>(f); }
}

// ---- split-bf16 helpers ----------------------------------------------------
__device__ __forceinline__ u32 f32_to_packed(float v) {
    u32 u = __float_as_uint(v);
    u32 hi = (u + 0x7FFFu + ((u >> 16) & 1u)) >> 16;      // RNE bf16 of v
    float vhi = __uint_as_float(hi << 16);
    float lof = v - vhi;
    u32 ul = __float_as_uint(lof);
    u32 lo = (ul + 0x7FFFu + ((ul >> 16) & 1u)) >> 16;    // RNE bf16 of residual
    return (hi << 16) | lo;
}
__device__ __forceinline__ float packed_f32(u32 w) {
    return __uint_as_float(w & 0xFFFF0000u) + __uint_as_float(w << 16);
}

// ---- fused weight pack: all 4 layers in one dispatch -----------------------
__device__ __forceinline__ void pack_one(const float* __restrict__ W,
                                         u16* __restrict__ Whi, u16* __restrict__ Wlo,
                                         int C, int O, int CT, int id) {
    int j = id & 7;
    int lane = (id >> 3) & 63;
    int fid = id >> 9;
    int NTt = O >> 5;
    int nt = fid % NTt;
    int t = fid / NTt;
    int SUBS = CT >> 4;
    int sub = t % SUBS;
    int kk = (t / SUBS) % KN;
    int ct = t / (KN * SUBS);
    int q = lane >> 5, n = lane & 31;
    int o = nt * 32 + n;
    int c = ct * CT + sub * 16 + q * 8 + j;
    u32 pw = f32_to_packed(W[((size_t)o * C + c) * KN + kk]);
    Whi[id] = (u16)(pw >> 16);
    Wlo[id] = (u16)(pw & 0xFFFFu);
}

__global__ void __launch_bounds__(256) pack_all_kern(
    const float* W_in, u16* Whi_in, u16* Wlo_in,
    const float* W1, u16* Whi_1, u16* Wlo_1,
    const float* W2, u16* Whi_2, u16* Wlo_2,
    const float* Wo, u16* Whi_o, u16* Wlo_o) {
    const int T0 = KN * 32 * 256;            // conv_in (CT=32)
    const int T1 = T0 + KN * 256 * 512;      // conv1
    const int T2 = T1 + KN * 512 * 256;      // conv2
    const int T3 = T2 + KN * 256 * 32;       // conv_out
    int id = blockIdx.x * 256 + threadIdx.x;
    if (id < T0) pack_one(W_in, Whi_in, Wlo_in, 32, 256, 32, id);
    else if (id < T1) pack_one(W1, Whi_1, Wlo_1, 256, 512, 64, id - T0);
    else if (id < T2) pack_one(W2, Whi_2, Wlo_2, 512, 256, 64, id - T1);
    else if (id < T3) pack_one(Wo, Whi_o, Wlo_o, 256, 32, 64, id - T2);
}

// ---- 32x32x16 MFMA comb-conv, WM=4/WN=1 measured-best geometry -------------
// Batch-generalized: global batch bg in [bbase, bbase+2*gridDim.x); buffers
// indexed by (bg - bbase) and sized for NBb batches. SRC==1 selects feats0/
// feats1 by bg>=256. This lets ONE kernel serve both the per-net path
// (bbase=net*256, NBb=256, grid.x=128) and the merged 2-net path (bbase=0,
// NBb=512, grid.x=256 -> 1024 blocks = 4 blocks/CU; LDS 4x34.8KB=139<=160KB).
// Merging exists purely for wave-level overlap: per-CU pipe times (MFMA 67us,
// LDS-A 65+34us, B 22us for conv1) don't change, but 4 blocks/CU overlaps
// them toward max() instead of sum().
// SRC: 0 packed u32, 1 fp32 (pack inline), 2 combine-2-fp32-partials+BN+ReLU
// +packed-residual. OUTF32: fp32 partial plane indexed by blockIdx.z.
template <int CT, int WM, int WN, int SRC, bool BNR, bool OUTF32>
__global__ void __launch_bounds__(256, 2) mconv11(
    const u32* __restrict__ Xp, const float* __restrict__ Xf0,
    const float* __restrict__ Xf1,
    const float* __restrict__ pIn,
    const float* __restrict__ bnb, const float* __restrict__ bng,
    const float* __restrict__ bnB,
    const u32* __restrict__ resid,
    const u16* __restrict__ Whi, const u16* __restrict__ Wlo,
    const float* __restrict__ bias, const float* __restrict__ gamma,
    const float* __restrict__ beta,
    const int* __restrict__ nei,
    u32* __restrict__ outp, float* __restrict__ outf,
    int C, int O, int tpz, int bbase, int NBb) {
    constexpr int SUBS = CT >> 4;
    constexpr int S = KN * SUBS;           // K-steps per ct tile
    constexpr int NG = S / 2;              // groups of 2 steps
    constexpr int STRIDE = CT + 8;         // u16; rows 16B-aligned (72 or 40)
    constexpr int PLSZ = G60 * STRIDE;     // u16 per plane (16B-multiple)
    constexpr int NMG = 4 / WM;            // # m-groups
    constexpr int NRO = (WM == 4) ? 2 : WM;  // rowoff entries actually needed
    __shared__ u16 Xs[4 * PLSZ];           // [bb][plane][PLSZ]
    const int tid = threadIdx.x;
    const int lane = tid & 63;
    const int wv = tid >> 6;
    const int mg = wv % NMG;               // wave's m-group
    const int ng = wv / NMG;               // wave's n-group
    const int q = lane >> 5;
    const int m = lane & 31;
    const int bp = (int)blockIdx.x + (bbase >> 1);   // GLOBAL batch-pair
    const int NTt = O >> 5;
    const int nt0 = (int)blockIdx.y * (WM * WN) + ng * WN;  // wave n-tile base
    const int ct0 = (int)blockIdx.z * tpz;
    const size_t PLi = (size_t)NBb * C * G60;        // partial-plane stride
    float* outfz = OUTF32 ? (outf + (size_t)blockIdx.z * ((size_t)NBb * O * G60)) : nullptr;

    int rowoff[NRO][KN];
#pragma unroll
    for (int jj = 0; jj < NRO; ++jj) {
        int mts, base;
        if (WM == 4) { mts = jj; base = 0; }
        else {
            int s = mg * WM + jj;
            mts = s & 1;
            base = (s >> 1) * 2 * PLSZ;
        }
        int g = mts * 32 + m;
        int gl = (g < G60) ? g : 0;
#pragma unroll
        for (int kk = 0; kk < KN; ++kk)
            rowoff[jj][kk] = nei[gl * KN + kk] * STRIDE + base;
    }

    f32x16 acc[WM][WN];
#pragma unroll
    for (int j = 0; j < WM; ++j)
#pragma unroll
        for (int nt = 0; nt < WN; ++nt) acc[j][nt] = (f32x16)(0.f);

    short8 Bh[2][2][WN], Bl[2][2][WN];     // [buf][step-in-group][nt]

    for (int ct = ct0; ct < ct0 + tpz; ++ct) {
        const size_t fbase = ((size_t)(ct * S) * NTt + nt0) * 512 + (size_t)lane * 8;

        __syncthreads();
        constexpr int PAIRS = (CT / 2) * G60;
        for (int i = tid; i < 2 * PAIRS; i += 256) {
            int sb = (i >= PAIRS) ? 1 : 0;
            int r = i - sb * PAIRS;
            int ccp = (r * 17477) >> 20;   // r/60, exact for r<3840
            int g = r - ccp * G60;
            int cc = ccp * 2;
            const int bg = bp * 2 + sb;    // global batch
            const int bloc = bg - bbase;   // buffer-local batch
            u32 w0, w1;
            if (SRC == 0) {
                size_t cg0 = ((size_t)bloc * C + (size_t)ct * CT + cc) * G60 + g;
                w0 = Xp[cg0]; w1 = Xp[cg0 + G60];
            } else if (SRC == 1) {
                const float* Xf = (bg >= 256) ? Xf1 : Xf0;
                size_t cg0 = ((size_t)(bg & 255) * C + (size_t)ct * CT + cc) * G60 + g;
                w0 = f32_to_packed(Xf[cg0]); w1 = f32_to_packed(Xf[cg0 + G60]);
            } else {
                size_t cg0 = ((size_t)bloc * C + (size_t)ct * CT + cc) * G60 + g;
                int c0 = ct * CT + cc;
                float v0 = pIn[cg0] + pIn[PLi + cg0];
                float v1 = pIn[cg0 + G60] + pIn[PLi + cg0 + G60];
                v0 = fmaxf((v0 + bnb[c0]) * bng[c0] + bnB[c0], 0.f) + packed_f32(resid[cg0]);
                v1 = fmaxf((v1 + bnb[c0 + 1]) * bng[c0 + 1] + bnB[c0 + 1], 0.f) + packed_f32(resid[cg0 + G60]);
                w0 = f32_to_packed(v0); w1 = f32_to_packed(v1);
            }
            int rb = sb * 2 * PLSZ + g * STRIDE + cc;
            *(u32*)(Xs + rb) = (w0 >> 16) | (w1 & 0xFFFF0000u);          // hi plane
            *(u32*)(Xs + rb + PLSZ) = (w0 & 0xFFFFu) | (w1 << 16);       // lo plane
        }

        // group-0 B prefetch issued before the barrier (independent of LDS)
        sfor<0, 2>([&](auto uc) {
            constexpr int u = decltype(uc)::v;
            sfor<0, WN>([&](auto nc) {
                constexpr int nt = decltype(nc)::v;
                const size_t fb = fbase + ((size_t)u * NTt + nt) * 512;
                Bh[0][u][nt] = *reinterpret_cast<const short8*>(Whi + fb);
                Bl[0][u][nt] = *reinterpret_cast<const short8*>(Wlo + fb);
            });
        });
        __syncthreads();

        sfor<0, NG>([&](auto gc) {
            constexpr int g = decltype(gc)::v;
            constexpr int pb = g & 1;
            if constexpr (g + 1 < NG) {
                constexpr int pn = (g + 1) & 1;
                sfor<0, 2>([&](auto uc) {
                    constexpr int u = decltype(uc)::v;
                    constexpr int s = 2 * (g + 1) + u;
                    sfor<0, WN>([&](auto nc) {
                        constexpr int nt = decltype(nc)::v;
                        const size_t fb = fbase + ((size_t)s * NTt + nt) * 512;
                        Bh[pn][u][nt] = *reinterpret_cast<const short8*>(Whi + fb);
                        Bl[pn][u][nt] = *reinterpret_cast<const short8*>(Wlo + fb);
                    });
                });
            }
            // A fragments for group g: this wave's WM m-slots
            short8 Ah[2][WM], Al[2][WM];
            sfor<0, 2>([&](auto uc) {
                constexpr int u = decltype(uc)::v;
                constexpr int s = 2 * g + u;
                constexpr int kk = s / SUBS;
                constexpr int sub = s - kk * SUBS;
                sfor<0, WM>([&](auto jc) {
                    constexpr int j = decltype(jc)::v;
                    int off;
                    if constexpr (WM == 4)
                        off = rowoff[j & 1][kk] + (j >> 1) * 2 * PLSZ + sub * 16 + q * 8;
                    else
                        off = rowoff[j][kk] + sub * 16 + q * 8;
                    Ah[u][j] = *reinterpret_cast<const short8*>(Xs + off);
                    Al[u][j] = *reinterpret_cast<const short8*>(Xs + off + PLSZ);
                });
            });
            // MFMAs: 3 passes x WM x WN per step; K-order per acc unchanged
            sfor<0, 2>([&](auto uc) {
                constexpr int u = decltype(uc)::v;
                sfor<0, WN>([&](auto nc) {
                    constexpr int nt = decltype(nc)::v;
                    sfor<0, WM>([&](auto jc) {
                        constexpr int j = decltype(jc)::v;
                        acc[j][nt] = __builtin_amdgcn_mfma_f32_32x32x16_bf16(
                            Ah[u][j], Bh[pb][u][nt], acc[j][nt], 0, 0, 0);
                    });
                });
                sfor<0, WN>([&](auto nc) {
                    constexpr int nt = decltype(nc)::v;
                    sfor<0, WM>([&](auto jc) {
                        constexpr int j = decltype(jc)::v;
                        acc[j][nt] = __builtin_amdgcn_mfma_f32_32x32x16_bf16(
                            Ah[u][j], Bl[pb][u][nt], acc[j][nt], 0, 0, 0);
                    });
                });
                sfor<0, WN>([&](auto nc) {
                    constexpr int nt = decltype(nc)::v;
                    sfor<0, WM>([&](auto jc) {
                        constexpr int j = decltype(jc)::v;
                        acc[j][nt] = __builtin_amdgcn_mfma_f32_32x32x16_bf16(
                            Al[u][j], Bh[pb][u][nt], acc[j][nt], 0, 0, 0);
                    });
                });
            });
        });
    }

    // epilogue. C/D: col(o)=lane&31, row-in-tile = (r&3)+8*(r>>2)+4*q [m74/m101]
#pragma unroll
    for (int j = 0; j < WM; ++j) {
        const int s = mg * WM + j;
        const int bbs = s >> 1, mts = s & 1;
        const int bloc = bp * 2 + bbs - bbase;       // buffer-local batch
#pragma unroll
        for (int nt = 0; nt < WN; ++nt) {
            const int o = (nt0 + nt) * 32 + m;
            float bi = 0.f, ga = 1.f, be = 0.f;
            if (!OUTF32) { bi = bias[o]; if (BNR) { ga = gamma[o]; be = beta[o]; } }
#pragma unroll
            for (int grp = 0; grp < 4; ++grp) {
                const int g0 = mts * 32 + grp * 8 + q * 4;
                if (g0 < G60) {
                    size_t oi = ((size_t)bloc * O + o) * G60 + g0;
                    if (OUTF32) {
                        f32x4 v;
#pragma unroll
                        for (int rr = 0; rr < 4; ++rr) v[rr] = acc[j][nt][grp * 4 + rr];
                        *reinterpret_cast<f32x4*>(outfz + oi) = v;
                    } else {
                        u32x4 pv;
#pragma unroll
                        for (int rr = 0; rr < 4; ++rr) {
                            float v = acc[j][nt][grp * 4 + rr] + bi;
                            if (BNR) v = fmaxf(v * ga + be, 0.f);
                            pv[rr] = f32_to_packed(v);
                        }
                        *reinterpret_cast<u32x4*>(outp + oi) = pv;
                    }
                }
            }
        }
    }
}

// ---- finalize: sum 4 conv_out partials, BN+ReLU, +feats, norms; emits the
// feats passthrough. Batch-generalized like mconv11 (bbase/NBb). -------------
__global__ void __launch_bounds__(64) finalize_kern(
    const float* __restrict__ pout,          // [4][NBb][32][60] fp32 partials
    const float* __restrict__ feats0, const float* __restrict__ feats1,
    const float* __restrict__ bo, const float* __restrict__ go,
    const float* __restrict__ beo,
    float* __restrict__ of0, float* __restrict__ of1,
    float* __restrict__ oe0, float* __restrict__ oe1,
    float* __restrict__ oi0, float* __restrict__ oi1,
    int bbase, int NBb) {
    const int bloc = blockIdx.x;             // buffer-local batch
    const int bg = bloc + bbase;             // global batch
    const int net = bg >> 8;
    const int bl = bg & 255;
    const float* feats = net ? feats1 : feats0;
    float* out_feats = net ? of1 : of0;
    float* out_eqv = net ? oe1 : oe0;
    float* out_inv = net ? oi1 : oi0;
    const size_t PB = (size_t)NBb * 32 * G60;
    __shared__ float E[32 * G60];
    __shared__ float gnorm[G60];
    __shared__ float inv_pre[32];
    __shared__ float inv_nrm;
    const int tid = threadIdx.x;

    for (int i = tid; i < 32 * G60; i += 64) {
        int f = i / G60;
        size_t idx = (size_t)bloc * 1920 + i;
        size_t idf = (size_t)bl * 1920 + i;
        float ft = feats[idf];
        out_feats[idf] = ft;
        float s = pout[idx] + pout[PB + idx] + pout[2 * PB + idx] + pout[3 * PB + idx];
        float v = fmaxf((s + bo[f]) * go[f] + beo[f], 0.f);
        E[i] = v + ft;
    }
    __syncthreads();
    if (tid < G60) {
        float s = 0.f;
        for (int f = 0; f < 32; ++f) { float v = E[f * G60 + tid]; s += v * v; }
        gnorm[tid] = fmaxf(sqrtf(s), 1e-4f);
    }
    if (tid < 32) {
        float s = 0.f;
        for (int g = 0; g < G60; ++g) s += E[tid * G60 + g];
        inv_pre[tid] = s / 60.f;
    }
    __syncthreads();
    if (tid == 0) {
        float s = 0.f;
        for (int f = 0; f < 32; ++f) s += inv_pre[f] * inv_pre[f];
        inv_nrm = fmaxf(sqrtf(s), 1e-4f);
    }
    __syncthreads();
    for (int i = tid; i < 1920; i += 64) {
        int g = i % G60;
        out_eqv[(size_t)bl * 1920 + i] = E[i] / gnorm[g];
    }
    if (tid < 32) out_inv[bl * 32 + tid] = inv_pre[tid] / inv_nrm;
}

// ---- des2dr: 256 thr/block, 4-way channel split per rotation a -------------
__global__ void __launch_bounds__(256) des2dr_kern(
    const float* __restrict__ e0f, const float* __restrict__ e1f,
    const int* __restrict__ permu, int* __restrict__ pre_int,
    float* __restrict__ out_pre) {
    const int b = blockIdx.x;
    __shared__ float X0[32 * G60];
    __shared__ float X1[32 * G60];
    __shared__ float pc[256];
    __shared__ float cor[64];
    const int tid = threadIdx.x;
    for (int i = tid; i < 1920; i += 256) {
        X0[i] = e0f[(size_t)b * 1920 + i];
        X1[i] = e1f[(size_t)b * 1920 + i];
    }
    __syncthreads();
    const int a = tid >> 2, fc = tid & 3;
    float s = 0.f;
    if (a < G60) {
        for (int g = 0; g < G60; ++g) {
            int p = permu[a * G60 + g];
#pragma unroll
            for (int f = fc * 8; f < fc * 8 + 8; ++f) s += X0[f * G60 + p] * X1[f * G60 + g];
        }
    }
    pc[tid] = s;
    __syncthreads();
    if (tid < 64) cor[tid] = pc[4 * tid] + pc[4 * tid + 1] + pc[4 * tid + 2] + pc[4 * tid + 3];
    __syncthreads();
    if (tid == 0) {
        float best = cor[0];
        int bi = 0;
        for (int a2 = 1; a2 < G60; ++a2)
            if (cor[a2] > best) { best = cor[a2]; bi = a2; }  // first-max = jnp.argmax
        pre_int[b] = bi;
        out_pre[b] = (float)bi;
    }
}

__global__ void __launch_bounds__(256) ability_kern(
    const int* __restrict__ pre_int, const int* __restrict__ true_idx,
    float* __restrict__ out_ability, float* __restrict__ out_true) {
    __shared__ int cnt[256];
    const int t = threadIdx.x;
    cnt[t] = (pre_int[t] == true_idx[t]) ? 1 : 0;
    out_true[t] = (float)true_idx[t];
    __syncthreads();
    for (int s = 128; s > 0; s >>= 1) {
        if (t < s) cnt[t] += cnt[t + s];
        __syncthreads();
    }
    if (t == 0) out_ability[0] = (float)cnt[0] / 256.0f;
}

extern "C" void kernel_launch(void* const* d_in, const int* in_sizes, int n_in,
                              void* d_out, int out_size, void* d_ws, size_t ws_size,
                              hipStream_t stream) {
    const float* feats0 = (const float*)d_in[0];
    const float* feats1 = (const float*)d_in[1];
    const int* true_idx = (const int*)d_in[2];
    const int* nei = (const int*)d_in[3];
    const int* permu = (const int*)d_in[4];
    const float* W_in = (const float*)d_in[5];
    const float* b_in = (const float*)d_in[6];
    const float* W1 = (const float*)d_in[7];
    const float* b1 = (const float*)d_in[8];
    const float* g1 = (const float*)d_in[9];
    const float* be1 = (const float*)d_in[10];
    const float* W2 = (const float*)d_in[11];
    const float* b2 = (const float*)d_in[12];
    const float* g2 = (const float*)d_in[13];
    const float* be2 = (const float*)d_in[14];
    const float* Wo = (const float*)d_in[15];
    const float* bo = (const float*)d_in[16];
    const float* go = (const float*)d_in[17];
    const float* beo = (const float*)d_in[18];

    float* out = (float*)d_out;
    const size_t SZF = (size_t)256 * 32 * G60;  // 491520
    float* out_f0 = out;
    float* out_f1 = out + SZF;
    float* out_e0 = out + 2 * SZF;
    float* out_e1 = out + 3 * SZF;
    float* out_i0 = out + 4 * SZF;
    float* out_i1 = out_i0 + 256 * 32;
    float* out_ab = out_i1 + 256 * 32;
    float* out_tr = out_ab + 1;
    float* out_pr = out_tr + 256;

    char* p = (char*)d_ws;
    auto alloc = [&](size_t bytes) { char* r = p; p += (bytes + 255) & ~(size_t)255; return r; };
    const size_t NW_IN = (size_t)KN * 32 * 256;
    const size_t NW_1 = (size_t)KN * 256 * 512;
    const size_t NW_2 = (size_t)KN * 512 * 256;
    const size_t NW_O = (size_t)KN * 256 * 32;
    u16* Whi_in = (u16*)alloc(NW_IN * 2); u16* Wlo_in = (u16*)alloc(NW_IN * 2);
    u16* Whi_1 = (u16*)alloc(NW_1 * 2);   u16* Wlo_1 = (u16*)alloc(NW_1 * 2);
    u16* Whi_2 = (u16*)alloc(NW_2 * 2);   u16* Wlo_2 = (u16*)alloc(NW_2 * 2);
    u16* Whi_o = (u16*)alloc(NW_O * 2);   u16* Wlo_o = (u16*)alloc(NW_O * 2);

    // merged-path footprint: weights(14.5M) + dbuf512(31.5M) + fcbuf512(62.9M,
    // pout aliases into it) + p2_512(62.9M) + pre_int  ~= 171.8 MB
    const size_t MERGED_NEED = 173000000;    // conservative
    const bool merged = ws_size >= MERGED_NEED;

    // ---- fused weight pack (1 dispatch) ----
    {
        int total = KN * (32 * 256 + 256 * 512 + 512 * 256 + 256 * 32);
        pack_all_kern<<<dim3((total + 255) / 256), dim3(256), 0, stream>>>(
            W_in, Whi_in, Wlo_in, W1, Whi_1, Wlo_1, W2, Whi_2, Wlo_2, Wo, Whi_o, Wlo_o);
    }

    if (merged) {
        // ---- merged 2-net path: 1024-block conv dispatches, 4 blocks/CU ----
        u32* dbuf = (u32*)alloc((size_t)512 * 256 * G60 * 4);        // 31.5M
        u32* fcbuf = (u32*)alloc((size_t)512 * 512 * G60 * 4);       // 62.9M
        float* p2 = (float*)alloc((size_t)2 * 512 * 256 * G60 * 4);  // 62.9M
        float* pout = (float*)fcbuf;   // alias: fcbuf dead after conv2
        int* pre_int = (int*)alloc(512 * 4);

        // conv_in: 32 -> 256. grid (256,4) = 1024 blocks.
        mconv11<32, 2, 1, 1, false, false><<<dim3(256, 4, 1), dim3(256), 0, stream>>>(
            nullptr, feats0, feats1, nullptr, nullptr, nullptr, nullptr, nullptr,
            Whi_in, Wlo_in, b_in, nullptr, nullptr, nei, dbuf, nullptr,
            32, 256, 1, 0, 512);
        // conv1: 256 -> 512, BN+ReLU packed. grid (256,4) = 1024 blocks.
        mconv11<64, 4, 1, 0, true, false><<<dim3(256, 4, 1), dim3(256), 0, stream>>>(
            dbuf, nullptr, nullptr, nullptr, nullptr, nullptr, nullptr, nullptr,
            Whi_1, Wlo_1, b1, g1, be1, nei, fcbuf, nullptr,
            256, 512, 4, 0, 512);
        // conv2: 512 -> 256, fp32 partials z=2. grid (256,2,2) = 1024 blocks.
        mconv11<64, 4, 1, 0, false, true><<<dim3(256, 2, 2), dim3(256), 0, stream>>>(
            fcbuf, nullptr, nullptr, nullptr, nullptr, nullptr, nullptr, nullptr,
            Whi_2, Wlo_2, nullptr, nullptr, nullptr, nei, nullptr, p2,
            512, 256, 4, 0, 512);
        // conv_out: 256 -> 32, partials z=4. grid (256,1,4) = 1024 blocks.
        mconv11<64, 1, 1, 2, false, true><<<dim3(256, 1, 4), dim3(256), 0, stream>>>(
            nullptr, nullptr, nullptr, p2, b2, g2, be2, dbuf,
            Whi_o, Wlo_o, nullptr, nullptr, nullptr, nei, nullptr, pout,
            256, 32, 1, 0, 512);
        // finalize both nets: grid 512.
        finalize_kern<<<dim3(512), dim3(64), 0, stream>>>(
            pout, feats0, feats1, bo, go, beo,
            out_f0, out_f1, out_e0, out_e1, out_i0, out_i1, 0, 512);
    } else {
        // ---- fallback: exact round-4 per-net path (101 MB footprint) ----
        u32* dbuf = (u32*)alloc((size_t)256 * 256 * G60 * 4);
        u32* fcbuf = (u32*)alloc((size_t)256 * 512 * G60 * 4);
        float* p2 = (float*)alloc((size_t)2 * 256 * 256 * G60 * 4);
        float* pout = (float*)alloc((size_t)4 * SZF * 4);
        int* pre_int0 = (int*)alloc(256 * 4);

        for (int net = 0; net < 2; ++net) {
            const int bb = net * 256;
            mconv11<32, 2, 1, 1, false, false><<<dim3(128, 4, 1), dim3(256), 0, stream>>>(
                nullptr, feats0, feats1, nullptr, nullptr, nullptr, nullptr, nullptr,
                Whi_in, Wlo_in, b_in, nullptr, nullptr, nei, dbuf, nullptr,
                32, 256, 1, bb, 256);
            mconv11<64, 4, 1, 0, true, false><<<dim3(128, 4, 1), dim3(256), 0, stream>>>(
                dbuf, nullptr, nullptr, nullptr, nullptr, nullptr, nullptr, nullptr,
                Whi_1, Wlo_1, b1, g1, be1, nei, fcbuf, nullptr,
                256, 512, 4, bb, 256);
            mconv11<64, 4, 1, 0, false, true><<<dim3(128, 2, 2), dim3(256), 0, stream>>>(
                fcbuf, nullptr, nullptr, nullptr, nullptr, nullptr, nullptr, nullptr,
                Whi_2, Wlo_2, nullptr, nullptr, nullptr, nei, nullptr, p2,
                512, 256, 4, bb, 256);
            mconv11<64, 1, 1, 2, false, true><<<dim3(128, 1, 4), dim3(256), 0, stream>>>(
                nullptr, nullptr, nullptr, p2, b2, g2, be2, dbuf,
                Whi_o, Wlo_o, nullptr, nullptr, nullptr, nei, nullptr, pout,
                256, 32, 1, bb, 256);
            finalize_kern<<<dim3(256), dim3(64), 0, stream>>>(
                pout, feats0, feats1, bo, go, beo,
                out_f0, out_f1, out_e0, out_e1, out_i0, out_i1, bb, 256);
        }
        des2dr_kern<<<dim3(256), dim3(256), 0, stream>>>(out_e0, out_e1, permu, pre_int0, out_pr);
        ability_kern<<<dim3(1), dim3(256), 0, stream>>>(pre_int0, true_idx, out_ab, out_tr);
        (void)in_sizes; (void)n_in; (void)out_size;
        return;
    }

    {
        int* pre_int = (int*)alloc(256 * 4);
        des2dr_kern<<<dim3(256), dim3(256), 0, stream>>>(out_e0, out_e1, permu, pre_int, out_pr);
        ability_kern<<<dim3(1), dim3(256), 0, stream>>>(pre_int, true_idx, out_ab, out_tr);
    }

    (void)in_sizes; (void)n_in; (void)out_size; (void)ws_size;
}